// Round 1
// baseline (401.929 us; speedup 1.0000x reference)
//
#include <hip/hip_runtime.h>
#include <hip/hip_cooperative_groups.h>

typedef unsigned short u16;
typedef unsigned int u32;
typedef __attribute__((ext_vector_type(8))) short short8;
typedef __attribute__((ext_vector_type(4))) float floatx4;

namespace cg = cooperative_groups;

__device__ inline float bf2f(u16 h) {
  union { u32 u; float f; } v; v.u = ((u32)h) << 16; return v.f;
}
__device__ inline u16 f2bf(float f) {
  union { float f; u32 u; } v; v.f = f;
  u32 u = v.u;
  return (u16)((u + 0x7fffu + ((u >> 16) & 1u)) >> 16);
}
// dtype-generic load: isbf is wave-uniform (from sniffer flag)
__device__ inline float ldf(const void* p, int i, int isbf) {
  return isbf ? bf2f(((const u16*)p)[i]) : ((const float*)p)[i];
}

// ---------------- K0: input dtype sniffer ----------------
__global__ void sniff_kernel(const u32* __restrict__ w, int* __restrict__ flag) {
  __shared__ int cnt;
  if (threadIdx.x == 0) cnt = 0;
  __syncthreads();
  int c = 0;
  #pragma unroll
  for (int i = 0; i < 4; ++i) {
    u32 v = w[1024 + threadIdx.x * 4 + i];
    int e = (v >> 7) & 0xFF;          // exponent field of the low u16 as bf16
    if (e >= 96 && e <= 160) c++;
  }
  atomicAdd(&cnt, c);
  __syncthreads();
  if (threadIdx.x == 0) *flag = (cnt >= 154) ? 1 : 0;   // 60% of 256
}

// ---------------- K1: style linears (s[8,512], cw[35,512], cb[35,512]) ----------------
__global__ void styles_kernel(const void* __restrict__ style, const void* __restrict__ class_style,
                              const void* __restrict__ mod_w, const void* __restrict__ mod_b,
                              const void* __restrict__ cw_w, const void* __restrict__ cw_b,
                              const void* __restrict__ cb_w, const void* __restrict__ cb_b,
                              const int* __restrict__ flagp,
                              float* __restrict__ s, float* __restrict__ cw, float* __restrict__ cb) {
  const int isbf = *flagp;
  int row = blockIdx.x;  // 0..77
  const void *vec, *wm, *bias; float* out; int voff;
  if (row < 8)        { vec = style;       voff = row*512;        wm = mod_w; bias = mod_b; out = s  + row*512; }
  else if (row < 43)  { vec = class_style; voff = (row-8)*512;    wm = cw_w;  bias = cw_b;  out = cw + (row-8)*512; }
  else                { vec = class_style; voff = (row-43)*512;   wm = cb_w;  bias = cb_b;  out = cb + (row-43)*512; }
  __shared__ float v[512];
  for (int i = threadIdx.x; i < 512; i += 256) v[i] = ldf(vec, voff + i, isbf);
  __syncthreads();
  const float inv = 0.04419417382415922f;  // 1/sqrt(512)
  for (int o = threadIdx.x; o < 512; o += 256) {
    float acc = 0.f;
    if (isbf) {
      for (int k = 0; k < 512; ++k) acc += bf2f(((const u16*)wm)[o*512 + k]) * v[k];
    } else {
      const float4* wr = (const float4*)((const float*)wm + o*512);
      for (int k = 0; k < 128; ++k) {
        float4 p = wr[k];
        acc += p.x*v[k*4+0] + p.y*v[k*4+1] + p.z*v[k*4+2] + p.w*v[k*4+3];
      }
    }
    out[o] = acc * inv + ldf(bias, o, isbf);
  }
}

// ---------------- K2: weight prep: wT[ck][tap][cout][ci32] + wsqT[cin][cout] ----------------
__global__ void wprep_kernel(const void* __restrict__ weight, const int* __restrict__ flagp,
                             u16* __restrict__ wT, float* __restrict__ wsqT) {
  const int isbf = *flagp;
  const int co = blockIdx.x;
  __shared__ float wsmem[4608];
  for (int i = threadIdx.x; i < 4608; i += 256)
    wsmem[i] = ldf(weight, co*4608 + i, isbf);   // coalesced
  __syncthreads();
  for (int ci = threadIdx.x; ci < 512; ci += 256) {
    float sq = 0.f;
    const int ck = ci >> 5, cin = ci & 31;
    #pragma unroll
    for (int tap = 0; tap < 9; ++tap) {
      float fv = wsmem[ci*9 + tap];
      sq += fv*fv;
      wT[(size_t)(((ck*9 + tap)*512) + co)*32 + cin] = f2bf(fv);
    }
    wsqT[ci*512 + co] = sq;
  }
}

// ---------------- K3: x transpose+modulate: xT[b][ck][h][w][ci32] ----------------
__global__ void xtrans_kernel(const void* __restrict__ x, const float* __restrict__ s,
                              const int* __restrict__ flagp, u16* __restrict__ xT) {
  const int isbf = *flagp;
  const int t = threadIdx.x;
  const int w = t & 63, cq = t >> 6;
  const int b = blockIdx.z, h = blockIdx.y;
  const int ck = blockIdx.x;                 // ci chunk of 32
  const int ci0 = ck*32 + cq*8;
  float f[8];
  #pragma unroll
  for (int j = 0; j < 8; ++j) {
    float xv = ldf(x, (((b*512) + ci0 + j)*64 + h)*64 + w, isbf);
    f[j] = xv * s[b*512 + ci0 + j];
  }
  u32 outp[4];
  #pragma unroll
  for (int i = 0; i < 4; ++i)
    outp[i] = (u32)f2bf(f[2*i]) | ((u32)f2bf(f[2*i+1]) << 16);
  uint4 po = {outp[0], outp[1], outp[2], outp[3]};
  // 4 cq-quarters of a wave fill one full 64B (w,ck) line -> L2 write-combine
  *(uint4*)&xT[(size_t)((((b*16 + ck)*64 + h)*64 + w)*32) + cq*8] = po;
}

// ---------------- K4: MFMA conv + fused IN partials (+ optional fused epilogue) ----------------
// Per wave: 64 couts x (2 h x 64 w) via 4m x 8n 16x16x32 frags (0.375 ds_reads/MFMA).
// Block: 64 couts x 8 h x 64 w, 4 waves. Grid (hb 8, b 8, coutblk 8) = 512 = 2/CU.
// LDS: xs dr-major [dr10][q4][c66] 16B cells (42240 B) + wsm [tap9][q4][co^(q<<1)] (36864 B) = 79104 B.
// xs dr-major: q-stride 66 cells == 2 mod 8 clusters -> staging writes & frag reads hit
// distinct 4-bank clusters within each 8-lane phase group (was 2-way aliased q-major).
// FUSED=1: cooperative launch; after grid.sync() reduce partials -> mu/istd in-block,
// stage CLADE table+labels in (now free) LDS, write FINAL y once (saves 128 MiB HBM).
template<int FUSED>
__global__ __launch_bounds__(256, 2) void conv_t(const u16* __restrict__ xT, const u16* __restrict__ wT,
                                                 float* __restrict__ y, float* __restrict__ part,
                                                 const float* __restrict__ s, const float* __restrict__ wsqT,
                                                 const float* __restrict__ cw, const float* __restrict__ cb,
                                                 const int* __restrict__ label) {
  __shared__ __align__(16) u16 xs[10*4*66*8];
  __shared__ __align__(16) u16 wsm[9*4*64*8];
  const int tid = threadIdx.x;
  const int lane = tid & 63;
  const int wid = tid >> 6;
  const int hb = blockIdx.x, b = blockIdx.y;
  const int ct0 = blockIdx.z * 64;
  const int h0 = hb * 8;

  // zero column-halo cells (c==0, c==65) for all q 0..3, dr 0..9 (80 cells)
  if (tid < 80) {
    int q = tid / 20, rem = tid % 20, dr = rem >> 1, side = rem & 1;
    uint4 z = {0,0,0,0};
    *(uint4*)&xs[(((dr*4 + q)*66) + side*65)*8] = z;
  }

  floatx4 acc[4][8];
  #pragma unroll
  for (int i = 0; i < 4; ++i) {
    #pragma unroll
    for (int j = 0; j < 8; ++j) acc[i][j] = (floatx4)(0.f);
  }

  const int m = lane & 15, qd = lane >> 4;

  for (int ck = 0; ck < 16; ++ck) {
    __syncthreads();  // prev chunk's MFMA reads done (and halo zeros, 1st iter)

    // stage x: 2560 16B cells, 10/thread; global reads fully contiguous 1KB/wave
    #pragma unroll
    for (int j = 0; j < 10; ++j) {
      int g = tid + j*256;                    // 0..2559
      int q = g & 3, c64 = (g >> 2) & 63, dr = g >> 8;
      int hin = h0 + dr - 1;
      uint4 v = {0,0,0,0};
      if (hin >= 0 && hin <= 63)
        v = *(const uint4*)&xT[(size_t)((((b*16 + ck)*64 + hin)*64 + c64)*32) + q*8];
      *(uint4*)&xs[(((dr*4 + q)*66) + 1 + c64)*8] = v;
    }
    // stage w: 2304 16B cells, 9/thread; contiguous 1KB/wave
    #pragma unroll
    for (int j = 0; j < 9; ++j) {
      int g = tid + j*256;                    // 0..2303
      int q = g & 3, co = (g >> 2) & 63, tap = g >> 8;
      uint4 v = *(const uint4*)&wT[(size_t)(((ck*9 + tap)*512) + ct0 + co)*32 + q*8];
      *(uint4*)&wsm[(((tap*4 + q)*64) + (co ^ (q << 1)))*8] = v;
    }
    __syncthreads();

    #pragma unroll
    for (int tap = 0; tap < 9; ++tap) {
      const int k1 = tap / 3, k2 = tap - k1*3;
      short8 af[4], bfr[8];
      #pragma unroll
      for (int mi = 0; mi < 4; ++mi)
        af[mi] = *(const short8*)&wsm[(((tap*4 + qd)*64) + ((mi*16 + m) ^ (qd << 1)))*8];
      #pragma unroll
      for (int hh = 0; hh < 2; ++hh) {
        const int dr = wid*2 + hh + k1;       // 0..9
        #pragma unroll
        for (int nw = 0; nw < 4; ++nw)
          bfr[hh*4 + nw] = *(const short8*)&xs[(((dr*4 + qd)*66) + nw*16 + m + k2)*8];
      }
      #pragma unroll
      for (int ni = 0; ni < 8; ++ni) {
        #pragma unroll
        for (int mi = 0; mi < 4; ++mi)
          acc[mi][ni] = __builtin_amdgcn_mfma_f32_16x16x32_bf16(af[mi], bfr[ni], acc[mi][ni], 0, 0, 0);
      }
    }
  }

  // fused IN partials: per-cout sum / sumsq over this block's 8x64 tile
  float s1[16], s2[16];
  #pragma unroll
  for (int mi = 0; mi < 4; ++mi) {
    #pragma unroll
    for (int r = 0; r < 4; ++r) {
      float a = 0.f, aa = 0.f;
      #pragma unroll
      for (int ni = 0; ni < 8; ++ni) {
        float v = acc[mi][ni][r];
        a += v; aa += v*v;
      }
      s1[mi*4+r] = a; s2[mi*4+r] = aa;
    }
  }
  #pragma unroll
  for (int off = 1; off < 16; off <<= 1) {
    #pragma unroll
    for (int i = 0; i < 16; ++i) {
      s1[i] += __shfl_xor(s1[i], off, 64);
      s2[i] += __shfl_xor(s2[i], off, 64);
    }
  }
  __syncthreads();                 // all waves done reading xs for MFMA
  float* red = (float*)xs;         // reuse LDS: [wid][co][2] = 512 floats
  if (m == 0) {
    #pragma unroll
    for (int mi = 0; mi < 4; ++mi) {
      #pragma unroll
      for (int r = 0; r < 4; ++r) {
        int co = mi*16 + qd*4 + r;
        red[(wid*64 + co)*2 + 0] = s1[mi*4+r];
        red[(wid*64 + co)*2 + 1] = s2[mi*4+r];
      }
    }
  }
  __syncthreads();
  if (tid < 128) {
    int co = tid >> 1, which = tid & 1;
    float v = (red[(0*64+co)*2+which] + red[(1*64+co)*2+which])
            + (red[(2*64+co)*2+which] + red[(3*64+co)*2+which]);
    part[(size_t)(((b*8 + hb)*512) + ct0 + co)*2 + which] = v;
  }

  if constexpr (!FUSED) {
    // write y (pre-norm conv result, f32) into d_out; finalize+epi kernels follow
    #pragma unroll
    for (int mi = 0; mi < 4; ++mi) {
      #pragma unroll
      for (int hh = 0; hh < 2; ++hh) {
        const int h = h0 + wid*2 + hh;
        #pragma unroll
        for (int nw = 0; nw < 4; ++nw) {
          #pragma unroll
          for (int r = 0; r < 4; ++r) {
            int co = ct0 + mi*16 + qd*4 + r;    // C/D: row=(lane>>4)*4+reg, col=lane&15
            int w = nw*16 + m;
            y[(size_t)(((b*512) + co)*64 + h)*64 + w] = acc[mi][hh*4 + nw][r];
          }
        }
      }
    }
  } else {
    cg::this_grid().sync();        // part[] from all hb-blocks now visible

    // LDS reuse (all waves past MFMA + red phases):
    float2* tab   = (float2*)xs;                 // [35][65] float2 = 18200 B (65-pad spreads label banks)
    int*    labs  = (int*)wsm;                   // [512] = 2048 B
    float*  epred = (float*)(wsm + 2048);        // byte 4096: [4][64] floats = 1024 B
    float2* ms    = (float2*)(wsm + 4096);       // byte 8192: [64] float2 = 512 B

    for (int i = tid; i < 2240; i += 256) {      // 35 cls x 64 co, coalesced on co
      int cls = i >> 6, co = i & 63;
      tab[cls*65 + co] = make_float2(cw[cls*512 + ct0 + co], cb[cls*512 + ct0 + co]);
    }
    for (int i = tid; i < 512; i += 256)
      labs[i] = label[((b*64) + h0 + (i >> 6))*64 + (i & 63)];

    // eps = 1e-5 * sum_ci s^2 * wsqT + const  (exact; redundant per hb-block, L2-resident)
    {
      float ep = 0.f;
      const float* wsq_c = wsqT + ct0 + (tid & 63);
      const float* sb = s + b*512 + (tid >> 6)*128;
      const int cib = (tid >> 6)*128;
      #pragma unroll 4
      for (int k = 0; k < 128; ++k) {
        float sv = sb[k];
        ep += sv*sv * wsq_c[(size_t)(cib + k)*512];
      }
      epred[tid] = ep;
    }
    __syncthreads();

    if (tid < 64) {
      float S = 0.f, Q = 0.f;
      const float2* pv = (const float2*)part;
      #pragma unroll
      for (int hbb = 0; hbb < 8; ++hbb) {
        float2 p = pv[(size_t)((b*8 + hbb)*512) + ct0 + tid];
        S += p.x; Q += p.y;
      }
      float eps = 1e-5f*(epred[tid] + epred[64+tid] + epred[128+tid] + epred[192+tid])
                + 4.608e-10f;       // = eps_in/(scale*demod)^2, exact
      float mval = S * (1.f/4096.f);
      float var = fmaxf(Q * (1.f/4096.f) - mval*mval, 0.f);
      ms[tid] = make_float2(mval, rsqrtf(var + eps));
    }
    __syncthreads();

    // normalize + CLADE straight out of registers; single final y write
    #pragma unroll
    for (int mi = 0; mi < 4; ++mi) {
      #pragma unroll
      for (int hh = 0; hh < 2; ++hh) {
        const int h = h0 + wid*2 + hh;
        #pragma unroll
        for (int nw = 0; nw < 4; ++nw) {
          const int w = nw*16 + m;
          const int lab = labs[(wid*2 + hh)*64 + w];
          const float2* trow = tab + lab*65;
          #pragma unroll
          for (int r = 0; r < 4; ++r) {
            const int col = mi*16 + qd*4 + r;
            float2 msv = ms[col];               // 16-lane broadcast, conflict-free
            float2 wb = trow[col];
            float a = (acc[mi][hh*4 + nw][r] - msv.x) * msv.y;
            y[(size_t)(((b*512) + ct0 + col)*64 + h)*64 + w] = a*wb.x + wb.y;
          }
        }
      }
    }
  }
}

// ---------------- K5 (fallback): finalize mu/istd from partials + SS-eps term ----------------
__global__ void finalize_kernel(const float* __restrict__ part, const float* __restrict__ s,
                                const float* __restrict__ wsqT,
                                float* __restrict__ mu, float* __restrict__ istd) {
  const int gid = blockIdx.x*256 + threadIdx.x;   // 0..4095 = b*512+co
  const int b = gid >> 9, co = gid & 511;
  float S = 0.f, Q = 0.f;
  #pragma unroll
  for (int hb = 0; hb < 8; ++hb) {
    S += part[(size_t)(((b*8 + hb)*512) + co)*2 + 0];
    Q += part[(size_t)(((b*8 + hb)*512) + co)*2 + 1];
  }
  float SS = 0.f;
  for (int ci = 0; ci < 512; ++ci) {
    float sv = s[b*512 + ci];
    SS += sv*sv * wsqT[ci*512 + co];   // coalesced across threads
  }
  float mval = S * (1.f/4096.f);
  float var = fmaxf(Q * (1.f/4096.f) - mval*mval, 0.f);
  float eps = 1e-5f*SS + 4.608e-10f;   // = eps_in/(scale*demod)^2, exact
  mu[gid] = mval;
  istd[gid] = rsqrtf(var + eps);
}

// ---------------- K6 (fallback): normalize + CLADE (in place on d_out, f32) ----------------
__global__ void epi_kernel(float* __restrict__ y, const float* __restrict__ mu, const float* __restrict__ istd,
                           const float* __restrict__ cw, const float* __restrict__ cb,
                           const int* __restrict__ label) {
  __shared__ float2 tab[35];
  const int blk = blockIdx.x;          // 8192 = 4096 planes x 2 halves
  const int bc = blk >> 1, half = blk & 1;
  const int b = bc >> 9, co = bc & 511;
  const int t = threadIdx.x;
  if (t < 35) tab[t] = make_float2(cw[t*512 + co], cb[t*512 + co]);
  __syncthreads();
  const float mval = mu[bc], is = istd[bc];
  const int base = half*2048 + t*8;
  const int h = base >> 6, w = base & 63;
  float* yp = y + (size_t)bc*4096 + base;
  float4 v0 = *(const float4*)yp;
  float4 v1 = *(const float4*)(yp + 4);
  const int* lp = label + ((b*64) + h)*64 + w;
  float vin[8] = {v0.x, v0.y, v0.z, v0.w, v1.x, v1.y, v1.z, v1.w};
  float vout[8];
  #pragma unroll
  for (int i = 0; i < 8; ++i) {
    float a = (vin[i] - mval) * is;
    float2 wb = tab[lp[i]];
    vout[i] = a*wb.x + wb.y;
  }
  float4 o0 = {vout[0], vout[1], vout[2], vout[3]};
  float4 o1 = {vout[4], vout[5], vout[6], vout[7]};
  *(float4*)yp = o0;
  *(float4*)(yp + 4) = o1;
}

extern "C" void kernel_launch(void* const* d_in, const int* in_sizes, int n_in,
                              void* d_out, int out_size, void* d_ws, size_t ws_size,
                              hipStream_t stream) {
  (void)in_sizes; (void)n_in; (void)out_size; (void)ws_size;
  const void* input       = d_in[0];
  const void* style       = d_in[1];
  const void* class_style = d_in[2];
  const void* weight      = d_in[3];
  const void* mod_w       = d_in[4];
  const void* mod_b       = d_in[5];
  const void* cw_w        = d_in[6];
  const void* cw_b        = d_in[7];
  const void* cb_w        = d_in[8];
  const void* cb_b        = d_in[9];
  const int* label        = (const int*)d_in[10];
  float* y = (float*)d_out;                   // final output written directly in fused path

  char* ws = (char*)d_ws;
  u16*   xT   = (u16*)  (ws + 0);             // 33,554,432 B  [b][ck16][h][w][ci32] bf16
  u16*   wT   = (u16*)  (ws + 33554432);      //  4,718,592 B  [ck16][tap][cout][ci32] bf16
  float* wsqT = (float*)(ws + 38273024);      //  1,048,576 B  [cin][cout]
  float* s    = (float*)(ws + 39321600);      //     16,384 B  [b][ci]
  float* cw   = (float*)(ws + 39337984);      //     71,680 B  [ncls][cout]
  float* cb   = (float*)(ws + 39409664);      //     71,680 B
  float* mu   = (float*)(ws + 39481344);      //     16,384 B  (fallback only)
  float* istd = (float*)(ws + 39497728);      //     16,384 B  (fallback only)
  float* part = (float*)(ws + 39514112);      //    262,144 B  [b][hb8][cout][2]
  int*   flag = (int*)  (ws + 39776256);      //          4 B  (total 39,776,260 B)

  hipLaunchKernelGGL(sniff_kernel, dim3(1), dim3(64), 0, stream, (const u32*)weight, flag);
  hipLaunchKernelGGL(styles_kernel, dim3(78), dim3(256), 0, stream,
                     style, class_style, mod_w, mod_b, cw_w, cw_b, cb_w, cb_b,
                     (const int*)flag, s, cw, cb);
  hipLaunchKernelGGL(wprep_kernel, dim3(512), dim3(256), 0, stream, weight, (const int*)flag, wT, wsqT);
  hipLaunchKernelGGL(xtrans_kernel, dim3(16, 64, 8), dim3(256), 0, stream, input, s, (const int*)flag, xT);

  // cooperative fused conv+IN+CLADE (512 blocks = exactly 2/CU: LDS 2x79104<=160K, VGPR<=256)
  {
    const u16* a0 = xT; const u16* a1 = wT; float* a2 = y; float* a3 = part;
    const float* a4 = s; const float* a5 = wsqT; const float* a6 = cw; const float* a7 = cb;
    const int* a8 = label;
    void* args[] = {&a0, &a1, &a2, &a3, &a4, &a5, &a6, &a7, &a8};
    hipError_t ce = hipLaunchCooperativeKernel(conv_t<1>, dim3(8, 8, 8), dim3(256),
                                               args, 0, stream);
    if (ce != hipSuccess) {
      (void)hipGetLastError();  // clear; fall back to 3-kernel path
      hipLaunchKernelGGL((conv_t<0>), dim3(8, 8, 8), dim3(256), 0, stream,
                         xT, wT, y, part, s, wsqT, cw, cb, label);
      hipLaunchKernelGGL(finalize_kernel, dim3(16), dim3(256), 0, stream, part, s, wsqT, mu, istd);
      hipLaunchKernelGGL(epi_kernel, dim3(8192), dim3(256), 0, stream, y, mu, istd, cw, cb, label);
    }
  }
}

// Round 2
// 355.858 us; speedup vs baseline: 1.1295x; 1.1295x over previous
//
#include <hip/hip_runtime.h>

typedef unsigned short u16;
typedef unsigned int u32;
typedef __attribute__((ext_vector_type(8))) short short8;
typedef __attribute__((ext_vector_type(4))) float floatx4;

__device__ inline float bf2f(u16 h) {
  union { u32 u; float f; } v; v.u = ((u32)h) << 16; return v.f;
}
__device__ inline u16 f2bf(float f) {
  union { float f; u32 u; } v; v.f = f;
  u32 u = v.u;
  return (u16)((u + 0x7fffu + ((u >> 16) & 1u)) >> 16);
}
// dtype-generic load: isbf is wave-uniform (from sniffer flag)
__device__ inline float ldf(const void* p, int i, int isbf) {
  return isbf ? bf2f(((const u16*)p)[i]) : ((const float*)p)[i];
}

// ---------------- K0: input dtype sniffer + barrier-counter reset ----------------
__global__ void sniff_kernel(const u32* __restrict__ w, int* __restrict__ flag, int* __restrict__ bar) {
  bar[threadIdx.x] = 0;                // 64 threads zero the 64 group counters
  __shared__ int cnt;
  if (threadIdx.x == 0) cnt = 0;
  __syncthreads();
  int c = 0;
  #pragma unroll
  for (int i = 0; i < 4; ++i) {
    u32 v = w[1024 + threadIdx.x * 4 + i];
    int e = (v >> 7) & 0xFF;          // exponent field of the low u16 as bf16
    if (e >= 96 && e <= 160) c++;
  }
  atomicAdd(&cnt, c);
  __syncthreads();
  if (threadIdx.x == 0) *flag = (cnt >= 154) ? 1 : 0;   // 60% of 256
}

// ---------------- K1: style linears (s[8,512], cw[35,512], cb[35,512]) ----------------
__global__ void styles_kernel(const void* __restrict__ style, const void* __restrict__ class_style,
                              const void* __restrict__ mod_w, const void* __restrict__ mod_b,
                              const void* __restrict__ cw_w, const void* __restrict__ cw_b,
                              const void* __restrict__ cb_w, const void* __restrict__ cb_b,
                              const int* __restrict__ flagp,
                              float* __restrict__ s, float* __restrict__ cw, float* __restrict__ cb) {
  const int isbf = *flagp;
  int row = blockIdx.x;  // 0..77
  const void *vec, *wm, *bias; float* out; int voff;
  if (row < 8)        { vec = style;       voff = row*512;        wm = mod_w; bias = mod_b; out = s  + row*512; }
  else if (row < 43)  { vec = class_style; voff = (row-8)*512;    wm = cw_w;  bias = cw_b;  out = cw + (row-8)*512; }
  else                { vec = class_style; voff = (row-43)*512;   wm = cb_w;  bias = cb_b;  out = cb + (row-43)*512; }
  __shared__ float v[512];
  for (int i = threadIdx.x; i < 512; i += 256) v[i] = ldf(vec, voff + i, isbf);
  __syncthreads();
  const float inv = 0.04419417382415922f;  // 1/sqrt(512)
  for (int o = threadIdx.x; o < 512; o += 256) {
    float acc = 0.f;
    if (isbf) {
      for (int k = 0; k < 512; ++k) acc += bf2f(((const u16*)wm)[o*512 + k]) * v[k];
    } else {
      const float4* wr = (const float4*)((const float*)wm + o*512);
      for (int k = 0; k < 128; ++k) {
        float4 p = wr[k];
        acc += p.x*v[k*4+0] + p.y*v[k*4+1] + p.z*v[k*4+2] + p.w*v[k*4+3];
      }
    }
    out[o] = acc * inv + ldf(bias, o, isbf);
  }
}

// ---------------- K2: weight prep: wT[ck][tap][cout][ci32] + wsqT[cin][cout] ----------------
__global__ void wprep_kernel(const void* __restrict__ weight, const int* __restrict__ flagp,
                             u16* __restrict__ wT, float* __restrict__ wsqT) {
  const int isbf = *flagp;
  const int co = blockIdx.x;
  __shared__ float wsmem[4608];
  for (int i = threadIdx.x; i < 4608; i += 256)
    wsmem[i] = ldf(weight, co*4608 + i, isbf);   // coalesced
  __syncthreads();
  for (int ci = threadIdx.x; ci < 512; ci += 256) {
    float sq = 0.f;
    const int ck = ci >> 5, cin = ci & 31;
    #pragma unroll
    for (int tap = 0; tap < 9; ++tap) {
      float fv = wsmem[ci*9 + tap];
      sq += fv*fv;
      wT[(size_t)(((ck*9 + tap)*512) + co)*32 + cin] = f2bf(fv);
    }
    wsqT[ci*512 + co] = sq;
  }
}

// ---------------- K3: x transpose+modulate: xT[b][ck][h][w][ci32] ----------------
__global__ void xtrans_kernel(const void* __restrict__ x, const float* __restrict__ s,
                              const int* __restrict__ flagp, u16* __restrict__ xT) {
  const int isbf = *flagp;
  const int t = threadIdx.x;
  const int w = t & 63, cq = t >> 6;
  const int b = blockIdx.z, h = blockIdx.y;
  const int ck = blockIdx.x;                 // ci chunk of 32
  const int ci0 = ck*32 + cq*8;
  float f[8];
  #pragma unroll
  for (int j = 0; j < 8; ++j) {
    float xv = ldf(x, (((b*512) + ci0 + j)*64 + h)*64 + w, isbf);
    f[j] = xv * s[b*512 + ci0 + j];
  }
  u32 outp[4];
  #pragma unroll
  for (int i = 0; i < 4; ++i)
    outp[i] = (u32)f2bf(f[2*i]) | ((u32)f2bf(f[2*i+1]) << 16);
  uint4 po = {outp[0], outp[1], outp[2], outp[3]};
  // 4 cq-quarters of a wave fill one full 64B (w,ck) line -> L2 write-combine
  *(uint4*)&xT[(size_t)((((b*16 + ck)*64 + h)*64 + w)*32) + cq*8] = po;
}

// ---------------- K4: MFMA conv + fused IN partials (+ optional fused epilogue) ----------------
// Per wave: 64 couts x (2 h x 64 w) via 4m x 8n 16x16x32 frags (0.375 ds_reads/MFMA).
// Block: 64 couts x 8 h x 64 w, 4 waves. Grid (hb 8, b 8, coutblk 8) = 512 = 2/CU.
// LDS: xs dr-major [dr10][q4][c66] 16B cells (42240 B) + wsm [tap9][q4][co^(q<<1)] (36864 B) = 79104 B.
// FUSED=1: per-(b,ct0)-GROUP atomic barrier (8 hb-blocks each; NOT grid-wide — R1's
// cg::grid.sync() cost ~70us of full-device serialization + fine-grained-memory spin).
// Pattern: part stores -> threadfence(release) -> arrive -> overlap tab/labs/eps staging
// with peers' tail -> relaxed spin -> threadfence(acquire) -> read parts -> final y write.
template<int FUSED>
__global__ __launch_bounds__(256, 2) void conv_t(const u16* __restrict__ xT, const u16* __restrict__ wT,
                                                 float* __restrict__ y, float* __restrict__ part,
                                                 const float* __restrict__ s, const float* __restrict__ wsqT,
                                                 const float* __restrict__ cw, const float* __restrict__ cb,
                                                 const int* __restrict__ label, int* __restrict__ bar) {
  __shared__ __align__(16) u16 xs[10*4*66*8];
  __shared__ __align__(16) u16 wsm[9*4*64*8];
  const int tid = threadIdx.x;
  const int lane = tid & 63;
  const int wid = tid >> 6;
  const int hb = blockIdx.x, b = blockIdx.y;
  const int ct0 = blockIdx.z * 64;
  const int h0 = hb * 8;

  // zero column-halo cells (c==0, c==65) for all q 0..3, dr 0..9 (80 cells)
  if (tid < 80) {
    int q = tid / 20, rem = tid % 20, dr = rem >> 1, side = rem & 1;
    uint4 z = {0,0,0,0};
    *(uint4*)&xs[(((dr*4 + q)*66) + side*65)*8] = z;
  }

  floatx4 acc[4][8];
  #pragma unroll
  for (int i = 0; i < 4; ++i) {
    #pragma unroll
    for (int j = 0; j < 8; ++j) acc[i][j] = (floatx4)(0.f);
  }

  const int m = lane & 15, qd = lane >> 4;

  for (int ck = 0; ck < 16; ++ck) {
    __syncthreads();  // prev chunk's MFMA reads done (and halo zeros, 1st iter)

    // stage x: 2560 16B cells, 10/thread; global reads fully contiguous 1KB/wave
    #pragma unroll
    for (int j = 0; j < 10; ++j) {
      int g = tid + j*256;                    // 0..2559
      int q = g & 3, c64 = (g >> 2) & 63, dr = g >> 8;
      int hin = h0 + dr - 1;
      uint4 v = {0,0,0,0};
      if (hin >= 0 && hin <= 63)
        v = *(const uint4*)&xT[(size_t)((((b*16 + ck)*64 + hin)*64 + c64)*32) + q*8];
      *(uint4*)&xs[(((dr*4 + q)*66) + 1 + c64)*8] = v;
    }
    // stage w: 2304 16B cells, 9/thread; contiguous 1KB/wave
    #pragma unroll
    for (int j = 0; j < 9; ++j) {
      int g = tid + j*256;                    // 0..2303
      int q = g & 3, co = (g >> 2) & 63, tap = g >> 8;
      uint4 v = *(const uint4*)&wT[(size_t)(((ck*9 + tap)*512) + ct0 + co)*32 + q*8];
      *(uint4*)&wsm[(((tap*4 + q)*64) + (co ^ (q << 1)))*8] = v;
    }
    __syncthreads();

    #pragma unroll
    for (int tap = 0; tap < 9; ++tap) {
      const int k1 = tap / 3, k2 = tap - k1*3;
      short8 af[4], bfr[8];
      #pragma unroll
      for (int mi = 0; mi < 4; ++mi)
        af[mi] = *(const short8*)&wsm[(((tap*4 + qd)*64) + ((mi*16 + m) ^ (qd << 1)))*8];
      #pragma unroll
      for (int hh = 0; hh < 2; ++hh) {
        const int dr = wid*2 + hh + k1;       // 0..9
        #pragma unroll
        for (int nw = 0; nw < 4; ++nw)
          bfr[hh*4 + nw] = *(const short8*)&xs[(((dr*4 + qd)*66) + nw*16 + m + k2)*8];
      }
      #pragma unroll
      for (int ni = 0; ni < 8; ++ni) {
        #pragma unroll
        for (int mi = 0; mi < 4; ++mi)
          acc[mi][ni] = __builtin_amdgcn_mfma_f32_16x16x32_bf16(af[mi], bfr[ni], acc[mi][ni], 0, 0, 0);
      }
    }
  }

  // fused IN partials: per-cout sum / sumsq over this block's 8x64 tile
  float s1[16], s2[16];
  #pragma unroll
  for (int mi = 0; mi < 4; ++mi) {
    #pragma unroll
    for (int r = 0; r < 4; ++r) {
      float a = 0.f, aa = 0.f;
      #pragma unroll
      for (int ni = 0; ni < 8; ++ni) {
        float v = acc[mi][ni][r];
        a += v; aa += v*v;
      }
      s1[mi*4+r] = a; s2[mi*4+r] = aa;
    }
  }
  #pragma unroll
  for (int off = 1; off < 16; off <<= 1) {
    #pragma unroll
    for (int i = 0; i < 16; ++i) {
      s1[i] += __shfl_xor(s1[i], off, 64);
      s2[i] += __shfl_xor(s2[i], off, 64);
    }
  }
  __syncthreads();                 // all waves done reading xs for MFMA
  float* red = (float*)xs;         // reuse LDS: [wid][co][2] = 512 floats
  if (m == 0) {
    #pragma unroll
    for (int mi = 0; mi < 4; ++mi) {
      #pragma unroll
      for (int r = 0; r < 4; ++r) {
        int co = mi*16 + qd*4 + r;
        red[(wid*64 + co)*2 + 0] = s1[mi*4+r];
        red[(wid*64 + co)*2 + 1] = s2[mi*4+r];
      }
    }
  }
  __syncthreads();
  if (tid < 128) {
    int co = tid >> 1, which = tid & 1;
    float v = (red[(0*64+co)*2+which] + red[(1*64+co)*2+which])
            + (red[(2*64+co)*2+which] + red[(3*64+co)*2+which]);
    part[(size_t)(((b*8 + hb)*512) + ct0 + co)*2 + which] = v;
  }

  if constexpr (!FUSED) {
    // write y (pre-norm conv result, f32) into d_out; finalize+epi kernels follow
    #pragma unroll
    for (int mi = 0; mi < 4; ++mi) {
      #pragma unroll
      for (int hh = 0; hh < 2; ++hh) {
        const int h = h0 + wid*2 + hh;
        #pragma unroll
        for (int nw = 0; nw < 4; ++nw) {
          #pragma unroll
          for (int r = 0; r < 4; ++r) {
            int co = ct0 + mi*16 + qd*4 + r;    // C/D: row=(lane>>4)*4+reg, col=lane&15
            int w = nw*16 + m;
            y[(size_t)(((b*512) + co)*64 + h)*64 + w] = acc[mi][hh*4 + nw][r];
          }
        }
      }
    }
  } else {
    // ---- release part[] and arrive at the 8-block (b,ct0)-group barrier ----
    const int g = b*8 + blockIdx.z;
    __threadfence();               // writers (tid<128) flush part to device scope
    __syncthreads();               // arrive strictly after all fences (also: red[] reads done)
    if (tid == 0) atomicAdd(&bar[g], 1);

    // ---- overlapped staging while the 7 peer blocks finish (xs/wsm now free) ----
    float2* tab   = (float2*)xs;                 // [35][66] float2 = 18480 B (66: 16B-aligned rows)
    int*    labs  = (int*)wsm;                   // [512] = 2048 B
    float*  epred = (float*)(wsm + 2048);        // [256] floats = 1024 B
    float2* ms    = (float2*)(wsm + 3072);       // [64] float2 = 512 B

    for (int i = tid; i < 2240; i += 256) {      // 35 cls x 64 co, coalesced on co
      int cls = i >> 6, co = i & 63;
      tab[cls*66 + co] = make_float2(cw[cls*512 + ct0 + co], cb[cls*512 + ct0 + co]);
    }
    for (int i = tid; i < 512; i += 256)
      labs[i] = label[((b*64) + h0 + (i >> 6))*64 + (i & 63)];

    // eps = 1e-5 * sum_ci s^2 * wsqT + const  (exact; L2-resident reads)
    {
      float ep = 0.f;
      const float* wsq_c = wsqT + ct0 + (tid & 63);
      const float* sb = s + b*512 + (tid >> 6)*128;
      const int cib = (tid >> 6)*128;
      #pragma unroll 4
      for (int k = 0; k < 128; ++k) {
        float sv = sb[k];
        ep += sv*sv * wsq_c[(size_t)(cib + k)*512];
      }
      epred[tid] = ep;
    }
    __syncthreads();

    // ---- spin for the group's 8 arrivals (relaxed polls; acquire once after) ----
    if (tid == 0) {
      while (__hip_atomic_load(&bar[g], __ATOMIC_RELAXED, __HIP_MEMORY_SCOPE_AGENT) < 8)
        __builtin_amdgcn_s_sleep(2);
    }
    __syncthreads();
    __threadfence();               // acquire: subsequent part[] reads see peers' stores

    if (tid < 64) {
      float S = 0.f, Q = 0.f;
      const float2* pv = (const float2*)part;
      #pragma unroll
      for (int hbb = 0; hbb < 8; ++hbb) {
        float2 p = pv[(size_t)((b*8 + hbb)*512) + ct0 + tid];
        S += p.x; Q += p.y;
      }
      float eps = 1e-5f*(epred[tid] + epred[64+tid] + epred[128+tid] + epred[192+tid])
                + 4.608e-10f;       // = eps_in/(scale*demod)^2, exact
      float mval = S * (1.f/4096.f);
      float var = fmaxf(Q * (1.f/4096.f) - mval*mval, 0.f);
      ms[tid] = make_float2(mval, rsqrtf(var + eps));
    }
    __syncthreads();

    // normalize + CLADE straight out of registers; single final y write
    #pragma unroll
    for (int mi = 0; mi < 4; ++mi) {
      float2 msv[4];
      #pragma unroll
      for (int r = 0; r < 4; ++r) msv[r] = ms[mi*16 + qd*4 + r];
      #pragma unroll
      for (int hh = 0; hh < 2; ++hh) {
        const int h = h0 + wid*2 + hh;
        #pragma unroll
        for (int nw = 0; nw < 4; ++nw) {
          const int w = nw*16 + m;
          const int lab = labs[(wid*2 + hh)*64 + w];
          const float2* trow = tab + lab*66 + mi*16 + qd*4;   // 16B-aligned (66 even, col%4==0)
          float4 p0 = *(const float4*)&trow[0];
          float4 p2 = *(const float4*)&trow[2];
          float wx[4] = {p0.x, p0.z, p2.x, p2.z};
          float wy[4] = {p0.y, p0.w, p2.y, p2.w};
          float* yp = &y[(size_t)(((b*512) + ct0 + mi*16 + qd*4)*64 + h)*64 + w];
          #pragma unroll
          for (int r = 0; r < 4; ++r) {
            float a = (acc[mi][hh*4 + nw][r] - msv[r].x) * msv[r].y;
            yp[(size_t)r*4096] = a*wx[r] + wy[r];
          }
        }
      }
    }
  }
}

// ---------------- K5 (fallback): finalize mu/istd from partials + SS-eps term ----------------
__global__ void finalize_kernel(const float* __restrict__ part, const float* __restrict__ s,
                                const float* __restrict__ wsqT,
                                float* __restrict__ mu, float* __restrict__ istd) {
  const int gid = blockIdx.x*256 + threadIdx.x;   // 0..4095 = b*512+co
  const int b = gid >> 9, co = gid & 511;
  float S = 0.f, Q = 0.f;
  #pragma unroll
  for (int hb = 0; hb < 8; ++hb) {
    S += part[(size_t)(((b*8 + hb)*512) + co)*2 + 0];
    Q += part[(size_t)(((b*8 + hb)*512) + co)*2 + 1];
  }
  float SS = 0.f;
  for (int ci = 0; ci < 512; ++ci) {
    float sv = s[b*512 + ci];
    SS += sv*sv * wsqT[ci*512 + co];   // coalesced across threads
  }
  float mval = S * (1.f/4096.f);
  float var = fmaxf(Q * (1.f/4096.f) - mval*mval, 0.f);
  float eps = 1e-5f*SS + 4.608e-10f;   // = eps_in/(scale*demod)^2, exact
  mu[gid] = mval;
  istd[gid] = rsqrtf(var + eps);
}

// ---------------- K6 (fallback): normalize + CLADE (in place on d_out, f32) ----------------
__global__ void epi_kernel(float* __restrict__ y, const float* __restrict__ mu, const float* __restrict__ istd,
                           const float* __restrict__ cw, const float* __restrict__ cb,
                           const int* __restrict__ label) {
  __shared__ float2 tab[35];
  const int blk = blockIdx.x;          // 8192 = 4096 planes x 2 halves
  const int bc = blk >> 1, half = blk & 1;
  const int b = bc >> 9, co = bc & 511;
  const int t = threadIdx.x;
  if (t < 35) tab[t] = make_float2(cw[t*512 + co], cb[t*512 + co]);
  __syncthreads();
  const float mval = mu[bc], is = istd[bc];
  const int base = half*2048 + t*8;
  const int h = base >> 6, w = base & 63;
  float* yp = y + (size_t)bc*4096 + base;
  float4 v0 = *(const float4*)yp;
  float4 v1 = *(const float4*)(yp + 4);
  const int* lp = label + ((b*64) + h)*64 + w;
  float vin[8] = {v0.x, v0.y, v0.z, v0.w, v1.x, v1.y, v1.z, v1.w};
  float vout[8];
  #pragma unroll
  for (int i = 0; i < 8; ++i) {
    float a = (vin[i] - mval) * is;
    float2 wb = tab[lp[i]];
    vout[i] = a*wb.x + wb.y;
  }
  float4 o0 = {vout[0], vout[1], vout[2], vout[3]};
  float4 o1 = {vout[4], vout[5], vout[6], vout[7]};
  *(float4*)yp = o0;
  *(float4*)(yp + 4) = o1;
}

extern "C" void kernel_launch(void* const* d_in, const int* in_sizes, int n_in,
                              void* d_out, int out_size, void* d_ws, size_t ws_size,
                              hipStream_t stream) {
  (void)in_sizes; (void)n_in; (void)out_size; (void)ws_size;
  const void* input       = d_in[0];
  const void* style       = d_in[1];
  const void* class_style = d_in[2];
  const void* weight      = d_in[3];
  const void* mod_w       = d_in[4];
  const void* mod_b       = d_in[5];
  const void* cw_w        = d_in[6];
  const void* cw_b        = d_in[7];
  const void* cb_w        = d_in[8];
  const void* cb_b        = d_in[9];
  const int* label        = (const int*)d_in[10];
  float* y = (float*)d_out;                   // final output written directly in fused path

  char* ws = (char*)d_ws;
  u16*   xT   = (u16*)  (ws + 0);             // 33,554,432 B  [b][ck16][h][w][ci32] bf16
  u16*   wT   = (u16*)  (ws + 33554432);      //  4,718,592 B  [ck16][tap][cout][ci32] bf16
  float* wsqT = (float*)(ws + 38273024);      //  1,048,576 B  [cin][cout]
  float* s    = (float*)(ws + 39321600);      //     16,384 B  [b][ci]
  float* cw   = (float*)(ws + 39337984);      //     71,680 B  [ncls][cout]
  float* cb   = (float*)(ws + 39409664);      //     71,680 B
  float* mu   = (float*)(ws + 39481344);      //     16,384 B  (fallback only)
  float* istd = (float*)(ws + 39497728);      //     16,384 B  (fallback only)
  float* part = (float*)(ws + 39514112);      //    262,144 B  [b][hb8][cout][2]
  int*   flag = (int*)  (ws + 39776256);      //          4 B
  int*   bar  = (int*)  (ws + 39776260);      //        256 B  64 group counters (total 39,776,516 B)

  hipLaunchKernelGGL(sniff_kernel, dim3(1), dim3(64), 0, stream, (const u32*)weight, flag, bar);
  hipLaunchKernelGGL(styles_kernel, dim3(78), dim3(256), 0, stream,
                     style, class_style, mod_w, mod_b, cw_w, cw_b, cb_w, cb_b,
                     (const int*)flag, s, cw, cb);
  hipLaunchKernelGGL(wprep_kernel, dim3(512), dim3(256), 0, stream, weight, (const int*)flag, wT, wsqT);
  hipLaunchKernelGGL(xtrans_kernel, dim3(16, 64, 8), dim3(256), 0, stream, input, s, (const int*)flag, xT);

  // fused path requires all 512 blocks co-resident (group barrier). Validate once via
  // occupancy API (512 = 2/CU x 256 CU fits: LDS 2x79104<=160K, VGPR 128<=256@2waves).
  static int fused_ok = -1;
  if (fused_ok < 0) {
    int nb = 0, ncu = 0, dev = 0;
    hipError_t e1 = hipOccupancyMaxActiveBlocksPerMultiprocessor(&nb, conv_t<1>, 256, 0);
    hipError_t e2 = hipGetDevice(&dev);
    hipError_t e3 = hipDeviceGetAttribute(&ncu, hipDeviceAttributeMultiprocessorCount, dev);
    fused_ok = (e1 == hipSuccess && e2 == hipSuccess && e3 == hipSuccess &&
                (long)nb * (long)ncu >= 512) ? 1 : 0;
  }

  if (fused_ok) {
    hipLaunchKernelGGL((conv_t<1>), dim3(8, 8, 8), dim3(256), 0, stream,
                       xT, wT, y, part, s, wsqT, cw, cb, label, bar);
  } else {
    hipLaunchKernelGGL((conv_t<0>), dim3(8, 8, 8), dim3(256), 0, stream,
                       xT, wT, y, part, s, wsqT, cw, cb, label, bar);
    hipLaunchKernelGGL(finalize_kernel, dim3(16), dim3(256), 0, stream, part, s, wsqT, mu, istd);
    hipLaunchKernelGGL(epi_kernel, dim3(8192), dim3(256), 0, stream, y, mu, istd, cw, cb, label);
  }
}

// Round 3
// 330.904 us; speedup vs baseline: 1.2146x; 1.0754x over previous
//
#include <hip/hip_runtime.h>

typedef unsigned short u16;
typedef unsigned int u32;
typedef __attribute__((ext_vector_type(8))) short short8;
typedef __attribute__((ext_vector_type(4))) float floatx4;

__device__ inline float bf2f(u16 h) {
  union { u32 u; float f; } v; v.u = ((u32)h) << 16; return v.f;
}
__device__ inline u16 f2bf(float f) {
  union { float f; u32 u; } v; v.f = f;
  u32 u = v.u;
  return (u16)((u + 0x7fffu + ((u >> 16) & 1u)) >> 16);
}
// dtype-generic load: isbf is wave-uniform (from per-block sniffer)
__device__ inline float ldf(const void* p, int i, int isbf) {
  return isbf ? bf2f(((const u16*)p)[i]) : ((const float*)p)[i];
}

// ---------------- K1: fused prep ----------------
// One kernel, 8782 blocks, three roles (block-uniform branch):
//   [0,78)      styles rows  -> s[8][512], cw[35][512], cb[35][512]
//   [78,590)    wprep        -> wT[ck][tap][cout][ci32] bf16, wsqT2[co][ci]
//   [590,8782)  xtrans       -> xT[b][ck][h][w][ci32] bf16 (s recomputed in-block:
//                               32 wave-dot products over L2-hot mod_w; removes the
//                               styles->xtrans launch dependency => 7 kernels -> 3)
// dtype sniffer inlined per block (256 samples of weight[1024..1280), same threshold).
__global__ __launch_bounds__(256) void prep_kernel(
    const void* __restrict__ style, const void* __restrict__ class_style,
    const void* __restrict__ weight,
    const void* __restrict__ mod_w, const void* __restrict__ mod_b,
    const void* __restrict__ cw_w, const void* __restrict__ cw_b,
    const void* __restrict__ cb_w, const void* __restrict__ cb_b,
    const void* __restrict__ x,
    float* __restrict__ s, float* __restrict__ cw, float* __restrict__ cb,
    u16* __restrict__ wT, float* __restrict__ wsqT2, u16* __restrict__ xT) {
  __shared__ float smem[4608];       // union: styles v[512] | wprep wsmem[4608] | xtrans sv[512]+sl[32]
  __shared__ int cnt;
  const int t = threadIdx.x;

  // inline sniffer (same 256 u32 samples + threshold as the old sniff_kernel)
  if (t == 0) cnt = 0;
  __syncthreads();
  {
    u32 v = ((const u32*)weight)[1024 + t];
    int e = (v >> 7) & 0xFF;
    if (e >= 96 && e <= 160) atomicAdd(&cnt, 1);
  }
  __syncthreads();
  const int isbf = (cnt >= 154) ? 1 : 0;
  const int bid = blockIdx.x;

  if (bid < 78) {
    // ---- styles role ----
    int row = bid;
    const void *vec, *wm, *bias; float* out; int voff;
    if (row < 8)        { vec = style;       voff = row*512;      wm = mod_w; bias = mod_b; out = s  + row*512; }
    else if (row < 43)  { vec = class_style; voff = (row-8)*512;  wm = cw_w;  bias = cw_b;  out = cw + (row-8)*512; }
    else                { vec = class_style; voff = (row-43)*512; wm = cb_w;  bias = cb_b;  out = cb + (row-43)*512; }
    float* v = smem;
    for (int i = t; i < 512; i += 256) v[i] = ldf(vec, voff + i, isbf);
    __syncthreads();
    const float inv = 0.04419417382415922f;  // 1/sqrt(512)
    for (int o = t; o < 512; o += 256) {
      float acc = 0.f;
      if (isbf) {
        for (int k = 0; k < 512; ++k) acc += bf2f(((const u16*)wm)[o*512 + k]) * v[k];
      } else {
        const float4* wr = (const float4*)((const float*)wm + o*512);
        for (int k = 0; k < 128; ++k) {
          float4 p = wr[k];
          acc += p.x*v[k*4+0] + p.y*v[k*4+1] + p.z*v[k*4+2] + p.w*v[k*4+3];
        }
      }
      out[o] = acc * inv + ldf(bias, o, isbf);
    }
  } else if (bid < 590) {
    // ---- wprep role (wsqT transposed: [co][ci] for coalesced epilogue reads) ----
    const int co = bid - 78;
    float* wsmem = smem;
    for (int i = t; i < 4608; i += 256)
      wsmem[i] = ldf(weight, co*4608 + i, isbf);   // coalesced
    __syncthreads();
    for (int ci = t; ci < 512; ci += 256) {
      float sq = 0.f;
      const int ck = ci >> 5, cin = ci & 31;
      #pragma unroll
      for (int tap = 0; tap < 9; ++tap) {
        float fv = wsmem[ci*9 + tap];
        sq += fv*fv;
        wT[(size_t)(((ck*9 + tap)*512) + co)*32 + cin] = f2bf(fv);
      }
      wsqT2[(size_t)co*512 + ci] = sq;             // coalesced store
    }
  } else {
    // ---- xtrans role with in-block s ----
    const int r = bid - 590;
    const int ck = r & 15, h = (r >> 4) & 63, b = r >> 10;
    float* sv = smem;          // style vector [512]
    float* sl = smem + 512;    // s_local [32]
    for (int i = t; i < 512; i += 256) sv[i] = ldf(style, b*512 + i, isbf);
    __syncthreads();
    const int lane = t & 63, wv = t >> 6;
    const float inv = 0.04419417382415922f;
    #pragma unroll
    for (int p = 0; p < 8; ++p) {
      const int row = p*4 + wv;                  // 0..31
      const int ci = ck*32 + row;
      float partial = 0.f;
      if (isbf) {
        const u16* wr = (const u16*)mod_w + (size_t)ci*512 + lane*8;
        #pragma unroll
        for (int k = 0; k < 8; ++k) partial += bf2f(wr[k]) * sv[lane*8 + k];
      } else {
        const float4* wr = (const float4*)((const float*)mod_w + (size_t)ci*512 + lane*8);
        float4 p0 = wr[0], p1 = wr[1];
        partial += p0.x*sv[lane*8+0] + p0.y*sv[lane*8+1] + p0.z*sv[lane*8+2] + p0.w*sv[lane*8+3]
                 + p1.x*sv[lane*8+4] + p1.y*sv[lane*8+5] + p1.z*sv[lane*8+6] + p1.w*sv[lane*8+7];
      }
      #pragma unroll
      for (int off = 1; off < 64; off <<= 1) partial += __shfl_xor(partial, off, 64);
      if (lane == 0) sl[row] = partial * inv + ldf(mod_b, ci, isbf);
    }
    __syncthreads();
    const int w = t & 63, cq = t >> 6;
    float f[8];
    #pragma unroll
    for (int j = 0; j < 8; ++j) {
      float xv = ldf(x, (((b*512) + ck*32 + cq*8 + j)*64 + h)*64 + w, isbf);
      f[j] = xv * sl[cq*8 + j];
    }
    u32 outp[4];
    #pragma unroll
    for (int i = 0; i < 4; ++i)
      outp[i] = (u32)f2bf(f[2*i]) | ((u32)f2bf(f[2*i+1]) << 16);
    uint4 po = {outp[0], outp[1], outp[2], outp[3]};
    *(uint4*)&xT[(size_t)((((b*16 + ck)*64 + h)*64 + w)*32) + cq*8] = po;
  }
}

// ---------------- K2: MFMA conv + fused IN partial sums (unfused epilogue) ----------------
// Per wave: 64 couts x (2 h x 64 w) via 4m x 8n 16x16x32 frags (0.375 ds_reads/MFMA).
// Block: 64 couts x 8 h x 64 w, 4 waves. Grid (hb 8, b 8, coutblk 8) = 512 = 2/CU.
// LDS: xs dr-major [dr10][q4][c66] (42240 B) + wsm [tap9][q4][co^(q<<1)] (36864 B) = 79104 B.
// Swizzles (kept from R2): cut SQ_LDS_BANK_CONFLICT 1.81e7 -> 9.24e6.
// R1/R2 lesson: in-kernel global-sync epilogues cost >= the separate kernel; keep unfused.
__global__ __launch_bounds__(256, 2) void conv_kernel(const u16* __restrict__ xT, const u16* __restrict__ wT,
                                                      float* __restrict__ y, float* __restrict__ part) {
  __shared__ __align__(16) u16 xs[10*4*66*8];
  __shared__ __align__(16) u16 wsm[9*4*64*8];
  const int tid = threadIdx.x;
  const int lane = tid & 63;
  const int wid = tid >> 6;
  const int hb = blockIdx.x, b = blockIdx.y;
  const int ct0 = blockIdx.z * 64;
  const int h0 = hb * 8;

  // zero column-halo cells (c==0, c==65) for all q 0..3, dr 0..9 (80 cells)
  if (tid < 80) {
    int q = tid / 20, rem = tid % 20, dr = rem >> 1, side = rem & 1;
    uint4 z = {0,0,0,0};
    *(uint4*)&xs[(((dr*4 + q)*66) + side*65)*8] = z;
  }

  floatx4 acc[4][8];
  #pragma unroll
  for (int i = 0; i < 4; ++i) {
    #pragma unroll
    for (int j = 0; j < 8; ++j) acc[i][j] = (floatx4)(0.f);
  }

  const int m = lane & 15, qd = lane >> 4;

  for (int ck = 0; ck < 16; ++ck) {
    __syncthreads();  // prev chunk's MFMA reads done (and halo zeros, 1st iter)

    // stage x: 2560 16B cells, 10/thread; global reads fully contiguous 1KB/wave
    #pragma unroll
    for (int j = 0; j < 10; ++j) {
      int g = tid + j*256;                    // 0..2559
      int q = g & 3, c64 = (g >> 2) & 63, dr = g >> 8;
      int hin = h0 + dr - 1;
      uint4 v = {0,0,0,0};
      if (hin >= 0 && hin <= 63)
        v = *(const uint4*)&xT[(size_t)((((b*16 + ck)*64 + hin)*64 + c64)*32) + q*8];
      *(uint4*)&xs[(((dr*4 + q)*66) + 1 + c64)*8] = v;
    }
    // stage w: 2304 16B cells, 9/thread; contiguous 1KB/wave
    #pragma unroll
    for (int j = 0; j < 9; ++j) {
      int g = tid + j*256;                    // 0..2303
      int q = g & 3, co = (g >> 2) & 63, tap = g >> 8;
      uint4 v = *(const uint4*)&wT[(size_t)(((ck*9 + tap)*512) + ct0 + co)*32 + q*8];
      *(uint4*)&wsm[(((tap*4 + q)*64) + (co ^ (q << 1)))*8] = v;
    }
    __syncthreads();

    #pragma unroll
    for (int tap = 0; tap < 9; ++tap) {
      const int k1 = tap / 3, k2 = tap - k1*3;
      short8 af[4], bfr[8];
      #pragma unroll
      for (int mi = 0; mi < 4; ++mi)
        af[mi] = *(const short8*)&wsm[(((tap*4 + qd)*64) + ((mi*16 + m) ^ (qd << 1)))*8];
      #pragma unroll
      for (int hh = 0; hh < 2; ++hh) {
        const int dr = wid*2 + hh + k1;       // 0..9
        #pragma unroll
        for (int nw = 0; nw < 4; ++nw)
          bfr[hh*4 + nw] = *(const short8*)&xs[(((dr*4 + qd)*66) + nw*16 + m + k2)*8];
      }
      #pragma unroll
      for (int ni = 0; ni < 8; ++ni) {
        #pragma unroll
        for (int mi = 0; mi < 4; ++mi)
          acc[mi][ni] = __builtin_amdgcn_mfma_f32_16x16x32_bf16(af[mi], bfr[ni], acc[mi][ni], 0, 0, 0);
      }
    }
  }

  // write y (pre-norm conv result, f32) into d_out
  #pragma unroll
  for (int mi = 0; mi < 4; ++mi) {
    #pragma unroll
    for (int hh = 0; hh < 2; ++hh) {
      const int h = h0 + wid*2 + hh;
      #pragma unroll
      for (int nw = 0; nw < 4; ++nw) {
        #pragma unroll
        for (int r = 0; r < 4; ++r) {
          int co = ct0 + mi*16 + qd*4 + r;    // C/D: row=(lane>>4)*4+reg, col=lane&15
          int w = nw*16 + m;
          y[(size_t)(((b*512) + co)*64 + h)*64 + w] = acc[mi][hh*4 + nw][r];
        }
      }
    }
  }

  // fused IN partials: per-cout sum / sumsq over this block's 8x64 tile
  float s1[16], s2[16];
  #pragma unroll
  for (int mi = 0; mi < 4; ++mi) {
    #pragma unroll
    for (int r = 0; r < 4; ++r) {
      float a = 0.f, aa = 0.f;
      #pragma unroll
      for (int ni = 0; ni < 8; ++ni) {
        float v = acc[mi][ni][r];
        a += v; aa += v*v;
      }
      s1[mi*4+r] = a; s2[mi*4+r] = aa;
    }
  }
  #pragma unroll
  for (int off = 1; off < 16; off <<= 1) {
    #pragma unroll
    for (int i = 0; i < 16; ++i) {
      s1[i] += __shfl_xor(s1[i], off, 64);
      s2[i] += __shfl_xor(s2[i], off, 64);
    }
  }
  __syncthreads();                 // all waves done reading xs for MFMA
  float* red = (float*)xs;         // reuse LDS: [wid][co][2] = 512 floats
  if (m == 0) {
    #pragma unroll
    for (int mi = 0; mi < 4; ++mi) {
      #pragma unroll
      for (int r = 0; r < 4; ++r) {
        int co = mi*16 + qd*4 + r;
        red[(wid*64 + co)*2 + 0] = s1[mi*4+r];
        red[(wid*64 + co)*2 + 1] = s2[mi*4+r];
      }
    }
  }
  __syncthreads();
  if (tid < 128) {
    int co = tid >> 1, which = tid & 1;
    float v = (red[(0*64+co)*2+which] + red[(1*64+co)*2+which])
            + (red[(2*64+co)*2+which] + red[(3*64+co)*2+which]);
    part[(size_t)(((b*8 + hb)*512) + ct0 + co)*2 + which] = v;
  }
}

// ---------------- K3: finalize + normalize + CLADE (one block per (b,co) plane) ----------------
// Folds the old finalize_kernel in: SS from coalesced wsqT2[co][ci] row + part-sum ->
// mu/istd in-block, then 16 px/thread float4 normalize+CLADE in place on y.
__global__ __launch_bounds__(256) void epi_kernel(float* __restrict__ y, const float* __restrict__ part,
                                                  const float* __restrict__ s, const float* __restrict__ wsqT2,
                                                  const float* __restrict__ cw, const float* __restrict__ cb,
                                                  const int* __restrict__ label) {
  const int bc = blockIdx.x;           // 4096 = b*512+co
  const int b = bc >> 9, co = bc & 511;
  const int t = threadIdx.x;
  __shared__ float tabw[35], tabb[35];
  __shared__ float redp[4];
  __shared__ float2 msh;
  if (t < 35) { tabw[t] = cw[t*512 + co]; tabb[t] = cb[t*512 + co]; }

  // SS partial: thread t covers ci = t, t+256 (coalesced)
  const float* sb = s + b*512;
  const float* wq = wsqT2 + (size_t)co*512;
  float ep;
  {
    float s0 = sb[t], s1v = sb[t + 256];
    ep = s0*s0*wq[t] + s1v*s1v*wq[t + 256];
  }
  #pragma unroll
  for (int off = 1; off < 64; off <<= 1) ep += __shfl_xor(ep, off, 64);
  if ((t & 63) == 0) redp[t >> 6] = ep;
  __syncthreads();
  if (t == 0) {
    float SS = redp[0] + redp[1] + redp[2] + redp[3];
    float S = 0.f, Q = 0.f;
    const float2* pv = (const float2*)part;
    #pragma unroll
    for (int hb = 0; hb < 8; ++hb) {
      float2 p = pv[(size_t)((b*8 + hb)*512) + co];
      S += p.x; Q += p.y;
    }
    float mval = S * (1.f/4096.f);
    float var = fmaxf(Q * (1.f/4096.f) - mval*mval, 0.f);
    float eps = 1e-5f*SS + 4.608e-10f;   // = eps_in/(scale*demod)^2, exact
    msh = make_float2(mval, rsqrtf(var + eps));
  }
  __syncthreads();
  const float mval = msh.x, is = msh.y;

  float* yp = y + (size_t)bc*4096 + t*16;
  const int* lp = label + b*4096 + t*16;
  #pragma unroll
  for (int u = 0; u < 4; ++u) {
    float4 v = *(const float4*)(yp + u*4);
    int4 l = *(const int4*)(lp + u*4);
    float4 o;
    o.x = (v.x - mval)*is*tabw[l.x] + tabb[l.x];
    o.y = (v.y - mval)*is*tabw[l.y] + tabb[l.y];
    o.z = (v.z - mval)*is*tabw[l.z] + tabb[l.z];
    o.w = (v.w - mval)*is*tabw[l.w] + tabb[l.w];
    *(float4*)(yp + u*4) = o;
  }
}

extern "C" void kernel_launch(void* const* d_in, const int* in_sizes, int n_in,
                              void* d_out, int out_size, void* d_ws, size_t ws_size,
                              hipStream_t stream) {
  (void)in_sizes; (void)n_in; (void)out_size; (void)ws_size;
  const void* input       = d_in[0];
  const void* style       = d_in[1];
  const void* class_style = d_in[2];
  const void* weight      = d_in[3];
  const void* mod_w       = d_in[4];
  const void* mod_b       = d_in[5];
  const void* cw_w        = d_in[6];
  const void* cw_b        = d_in[7];
  const void* cb_w        = d_in[8];
  const void* cb_b        = d_in[9];
  const int* label        = (const int*)d_in[10];
  float* y = (float*)d_out;                   // f32 conv result in d_out, normalized in place

  char* ws = (char*)d_ws;
  u16*   xT    = (u16*)  (ws + 0);            // 33,554,432 B  [b][ck16][h][w][ci32] bf16
  u16*   wT    = (u16*)  (ws + 33554432);     //  4,718,592 B  [ck16][tap][cout][ci32] bf16
  float* wsqT2 = (float*)(ws + 38273024);     //  1,048,576 B  [cout][cin]
  float* s     = (float*)(ws + 39321600);     //     16,384 B  [b][ci]
  float* cw    = (float*)(ws + 39337984);     //     71,680 B  [ncls][cout]
  float* cb    = (float*)(ws + 39409664);     //     71,680 B
  float* part  = (float*)(ws + 39481344);     //    262,144 B  [b][hb8][cout][2]  (total 39,743,488 B)

  // 3 launches (was 7): inter-kernel gaps measured ~20-25us each dominate the pipeline.
  hipLaunchKernelGGL(prep_kernel, dim3(8782), dim3(256), 0, stream,
                     style, class_style, weight, mod_w, mod_b, cw_w, cw_b, cb_w, cb_b,
                     input, s, cw, cb, wT, wsqT2, xT);
  hipLaunchKernelGGL(conv_kernel, dim3(8, 8, 8), dim3(256), 0, stream, xT, wT, y, part);
  hipLaunchKernelGGL(epi_kernel, dim3(4096), dim3(256), 0, stream, y, part, s, wsqT2, cw, cb, label);
}